// Round 6
// baseline (237.529 us; speedup 1.0000x reference)
//
#include <hip/hip_runtime.h>
#include <float.h>

#define NUM_HEADS    32
#define NUM_KV_HEADS 8
#define HEAD_SIZE    128
#define Q_PER_KV     4
#define BLOCK_SZ     16
#define MAX_BLOCKS   128
#define SCALE        0.08838834764831845f

#define CHUNK_BLOCKS 16                           // cache blocks per chunk (R2-proven)
#define CHUNK_TOK    (CHUNK_BLOCKS * BLOCK_SZ)    // 256 tokens
#define NCHUNK       (MAX_BLOCKS / CHUNK_BLOCKS)  // 8
#define WS_STRIDE    528            // 8 (m,l) + 512 (O), 64B-multiple
// counters live at a 32MB byte offset into ws (records use < 9MB)
#define CTR_FLT_OFF  (8u * 1024u * 1024u)

typedef float v4f __attribute__((ext_vector_type(4)));

// Fused: per-chunk partial attention + last-arriving-WG merge.
// grid (NUM_KV_HEADS, BATCH, NCHUNK) -- c slowest (R2 layout). 64 thr = 1 wave.
__global__ __launch_bounds__(64, 4)
void paged_attn_fused(const float* __restrict__ query,
                      const float* __restrict__ k_new,
                      const float* __restrict__ v_new,
                      const float* __restrict__ key_cache,
                      const float* __restrict__ value_cache,
                      const int* __restrict__ block_tables,
                      const int* __restrict__ context_lens,
                      float* __restrict__ ws,
                      int* __restrict__ ctr,
                      float* __restrict__ out) {
    const int h   = blockIdx.x;
    const int b   = blockIdx.y;
    const int c   = blockIdx.z;
    const int tid = threadIdx.x;  // 0..63

    const int ctx = context_lens[b];
    const int nb  = (ctx + BLOCK_SZ - 1) / BLOCK_SZ;
    const int b0  = c * CHUNK_BLOCKS;
    if (b0 >= nb) return;                       // inactive chunk
    const int nbl  = min(nb - b0, CHUNK_BLOCKS);
    const int nch  = (nb + CHUNK_BLOCKS - 1) / CHUNK_BLOCKS;  // active chunks
    const int last = ctx - 1;                   // stale cache slot -> masked

    __shared__ float q_lds[Q_PER_KV * HEAD_SIZE];   // 2 KB, pre-scaled
    __shared__ float s_lds[Q_PER_KV * CHUNK_TOK];   // 4 KB scores -> probs
    __shared__ int   old_lds;

    // ---- stage Q (512 floats = 128 v4f), folding SCALE ----
    {
        const v4f* qg = reinterpret_cast<const v4f*>(
            query + ((size_t)b * NUM_HEADS + h * Q_PER_KV) * HEAD_SIZE);
        v4f* ql = reinterpret_cast<v4f*>(q_lds);
        ql[tid]      = qg[tid]      * SCALE;
        ql[tid + 64] = qg[tid + 64] * SCALE;
    }
    __syncthreads();

    // ---- scores: 4 lanes per cache block (R2-exact) ----
    {
        const int bil = tid >> 2;   // 0..15
        const int o   = tid & 3;
        if (bil < nbl) {
            const int phys = block_tables[b * MAX_BLOCKS + b0 + bil];
            const v4f* kp = reinterpret_cast<const v4f*>(key_cache) +
                            ((size_t)phys * NUM_KV_HEADS + h) * (HEAD_SIZE * BLOCK_SZ / 4);
            const v4f* q4 = reinterpret_cast<const v4f*>(q_lds);
            v4f acc[Q_PER_KV];
            #pragma unroll
            for (int qh = 0; qh < Q_PER_KV; ++qh) acc[qh] = (v4f)0.f;
            #pragma unroll 4
            for (int d4 = 0; d4 < HEAD_SIZE / 4; ++d4) {
                v4f k[4];
                #pragma unroll
                for (int dd = 0; dd < 4; ++dd) k[dd] = kp[d4 * 16 + dd * 4 + o];
                #pragma unroll
                for (int qh = 0; qh < Q_PER_KV; ++qh) {
                    const v4f qv = q4[qh * (HEAD_SIZE / 4) + d4];
                    #pragma unroll
                    for (int dd = 0; dd < 4; ++dd) acc[qh] += qv[dd] * k[dd];
                }
            }
            const int t0 = bil * BLOCK_SZ + o * 4;      // chunk-local token
            const int g0 = b0 * BLOCK_SZ + t0;          // global token
            #pragma unroll
            for (int qh = 0; qh < Q_PER_KV; ++qh) {
                v4f sv;
                #pragma unroll
                for (int j = 0; j < 4; ++j) {
                    const int g = g0 + j;
                    sv[j] = (g < ctx && g != last) ? acc[qh][j] : -FLT_MAX;
                }
                *reinterpret_cast<v4f*>(&s_lds[qh * CHUNK_TOK + t0]) = sv;
            }
        }
    }
    __syncthreads();

    // ---- prefetch first V block into regs (overlaps softmax) ----
    const int d0 = tid, d1 = tid + 64;
    v4f cur0[4], cur1[4];
    {
        const int phys = block_tables[b * MAX_BLOCKS + b0];
        const v4f* vp = reinterpret_cast<const v4f*>(value_cache) +
                        ((size_t)phys * NUM_KV_HEADS + h) * (HEAD_SIZE * BLOCK_SZ / 4);
        #pragma unroll
        for (int j = 0; j < 4; ++j) { cur0[j] = vp[d0 * 4 + j]; cur1[j] = vp[d1 * 4 + j]; }
    }

    // ---- chunk-local softmax (un-normalized), qh sequential (R2-exact) ----
    float* wsp = ws + (((size_t)b * NUM_KV_HEADS + h) * NCHUNK + c) * WS_STRIDE;
    {
        const int T = nbl * BLOCK_SZ;   // <= 256
        #pragma unroll
        for (int qh = 0; qh < Q_PER_KV; ++qh) {
            float m = -FLT_MAX;
            for (int t = tid; t < T; t += 64) m = fmaxf(m, s_lds[qh * CHUNK_TOK + t]);
            #pragma unroll
            for (int off = 32; off; off >>= 1) m = fmaxf(m, __shfl_xor(m, off));
            float l = 0.f;
            for (int t = tid; t < T; t += 64) {
                const float s = s_lds[qh * CHUNK_TOK + t];
                const float p = (s == -FLT_MAX) ? 0.f : __expf(s - m);
                s_lds[qh * CHUNK_TOK + t] = p;
                l += p;
            }
            #pragma unroll
            for (int off = 32; off; off >>= 1) l += __shfl_xor(l, off);
            if (tid == 0) { wsp[qh] = m; wsp[Q_PER_KV + qh] = l; }
        }
    }
    __syncthreads();

    // ---- partial PV: lane owns dims {d0,d1}; V double-buffered ----
    {
        float acc0[Q_PER_KV] = {0.f, 0.f, 0.f, 0.f};
        float acc1[Q_PER_KV] = {0.f, 0.f, 0.f, 0.f};
        for (int bil = 0; bil < nbl; ++bil) {
            v4f nxt0[4], nxt1[4];
            if (bil + 1 < nbl) {
                const int physn = block_tables[b * MAX_BLOCKS + b0 + bil + 1];
                const v4f* vpn = reinterpret_cast<const v4f*>(value_cache) +
                                 ((size_t)physn * NUM_KV_HEADS + h) * (HEAD_SIZE * BLOCK_SZ / 4);
                #pragma unroll
                for (int j = 0; j < 4; ++j) { nxt0[j] = vpn[d0 * 4 + j]; nxt1[j] = vpn[d1 * 4 + j]; }
            }
            #pragma unroll
            for (int qh = 0; qh < Q_PER_KV; ++qh) {
                const v4f* pq = reinterpret_cast<const v4f*>(
                    &s_lds[qh * CHUNK_TOK + bil * BLOCK_SZ]);
                #pragma unroll
                for (int j = 0; j < 4; ++j) {
                    const v4f p = pq[j];
                    acc0[qh] += p[0]*cur0[j][0] + p[1]*cur0[j][1] + p[2]*cur0[j][2] + p[3]*cur0[j][3];
                    acc1[qh] += p[0]*cur1[j][0] + p[1]*cur1[j][1] + p[2]*cur1[j][2] + p[3]*cur1[j][3];
                }
            }
            if (bil + 1 < nbl) {
                #pragma unroll
                for (int j = 0; j < 4; ++j) { cur0[j] = nxt0[j]; cur1[j] = nxt1[j]; }
            }
        }
        float* wo = wsp + 2 * Q_PER_KV;
        #pragma unroll
        for (int qh = 0; qh < Q_PER_KV; ++qh) {
            wo[qh * HEAD_SIZE + d0] = acc0[qh];
            wo[qh * HEAD_SIZE + d1] = acc1[qh];
        }
    }

    // ---- signal completion; last WG of this (b,h) merges ----
    __syncthreads();                 // all lanes' stores issued (wave-uniform)
    __threadfence();                 // drain + L2 writeback (cross-XCD visibility)
    if (tid == 0) old_lds = atomicAdd(&ctr[b * NUM_KV_HEADS + h], 1);
    __syncthreads();
    if (old_lds != nch - 1) return;
    __threadfence();                 // acquire: invalidate stale lines before reads

    // ====== merge path (one WG per (b,h)) ======
    {
        const float* wsb = ws + ((size_t)b * NUM_KV_HEADS + h) * NCHUNK * WS_STRIDE;
        float M[Q_PER_KV], L[Q_PER_KV], a0[Q_PER_KV], a1[Q_PER_KV];
        #pragma unroll
        for (int qh = 0; qh < Q_PER_KV; ++qh) { M[qh] = -FLT_MAX; L[qh] = 0.f; a0[qh] = 0.f; a1[qh] = 0.f; }

        for (int cc = 0; cc < nch; ++cc) {
            const float* rp = wsb + (size_t)cc * WS_STRIDE;
            #pragma unroll
            for (int qh = 0; qh < Q_PER_KV; ++qh) {
                const float mc = rp[qh];
                const float lc = rp[Q_PER_KV + qh];
                const float o0 = rp[2 * Q_PER_KV + qh * HEAD_SIZE + d0];
                const float o1 = rp[2 * Q_PER_KV + qh * HEAD_SIZE + d1];
                const float nM = fmaxf(M[qh], mc);
                const float eM = __expf(M[qh] - nM), ec = __expf(mc - nM);
                a0[qh] = a0[qh] * eM + o0 * ec;
                a1[qh] = a1[qh] * eM + o1 * ec;
                L[qh]  = L[qh]  * eM + lc * ec;
                M[qh]  = nM;
            }
        }
        // new token: exact from k_new/v_new (q_lds already pre-scaled)
        const float* kn = k_new + ((size_t)b * NUM_KV_HEADS + h) * HEAD_SIZE;
        const float* vn = v_new + ((size_t)b * NUM_KV_HEADS + h) * HEAD_SIZE;
        const float kn0 = kn[d0], kn1 = kn[d1];
        const float vn0 = vn[d0], vn1 = vn[d1];
        #pragma unroll
        for (int qh = 0; qh < Q_PER_KV; ++qh) {
            float s = q_lds[qh * HEAD_SIZE + d0] * kn0 + q_lds[qh * HEAD_SIZE + d1] * kn1;
            #pragma unroll
            for (int off = 32; off; off >>= 1) s += __shfl_xor(s, off);
            const float nM = fmaxf(M[qh], s);
            const float eM = __expf(M[qh] - nM), es = __expf(s - nM);
            a0[qh] = a0[qh] * eM + es * vn0;
            a1[qh] = a1[qh] * eM + es * vn1;
            L[qh]  = L[qh]  * eM + es;
        }
        float* ob = out + ((size_t)b * NUM_HEADS + h * Q_PER_KV) * HEAD_SIZE;
        #pragma unroll
        for (int qh = 0; qh < Q_PER_KV; ++qh) {
            const float inv = 1.0f / L[qh];
            ob[qh * HEAD_SIZE + d0] = a0[qh] * inv;
            ob[qh * HEAD_SIZE + d1] = a1[qh] * inv;
        }
    }
}

extern "C" void kernel_launch(void* const* d_in, const int* in_sizes, int n_in,
                              void* d_out, int out_size, void* d_ws, size_t ws_size,
                              hipStream_t stream) {
    const float* query       = (const float*)d_in[0];
    const float* k_new       = (const float*)d_in[1];
    const float* v_new       = (const float*)d_in[2];
    const float* key_cache   = (const float*)d_in[3];
    const float* value_cache = (const float*)d_in[4];
    const int*   block_tables  = (const int*)d_in[5];
    const int*   context_lens  = (const int*)d_in[6];
    float* out = (float*)d_out;
    float* ws  = (float*)d_ws;
    int*   ctr = (int*)(ws + CTR_FLT_OFF);

    const int batch = in_sizes[6];

    // zero the per-(b,h) completion counters (graph-capturable)
    hipMemsetAsync(ctr, 0, batch * NUM_KV_HEADS * sizeof(int), stream);

    dim3 g(NUM_KV_HEADS, batch, NCHUNK);   // c slowest (R2 layout)
    paged_attn_fused<<<g, 64, 0, stream>>>(query, k_new, v_new,
                                           key_cache, value_cache,
                                           block_tables, context_lens,
                                           ws, ctr, out);
}

// Round 7
// 234.855 us; speedup vs baseline: 1.0114x; 1.0114x over previous
//
#include <hip/hip_runtime.h>
#include <float.h>

#define NUM_HEADS    32
#define NUM_KV_HEADS 8
#define HEAD_SIZE    128
#define Q_PER_KV     4
#define BLOCK_SZ     16
#define MAX_BLOCKS   128
#define SCALE        0.08838834764831845f

#define CHUNK_BLOCKS 16                           // R2-proven
#define CHUNK_TOK    (CHUNK_BLOCKS * BLOCK_SZ)    // 256 tokens
#define NCHUNK       (MAX_BLOCKS / CHUNK_BLOCKS)  // 8
#define WS_STRIDE    528                          // 8 (m,l) + 512 (O)
#define CTR_FLT_OFF  (8u * 1024u * 1024u)         // counters 32MB into ws

typedef float v4f __attribute__((ext_vector_type(4)));

// grid (NUM_KV_HEADS, BATCH, NCHUNK+1), c slowest. 64 threads = 1 wave.
// c < NCHUNK : R2-exact chunk partial attention.
// c == NCHUNK: merge WG — spin-waits for this (b,h)'s chunks, then merges.
__global__ __launch_bounds__(64, 4)
void paged_attn_fused(const float* __restrict__ query,
                      const float* __restrict__ k_new,
                      const float* __restrict__ v_new,
                      const float* __restrict__ key_cache,
                      const float* __restrict__ value_cache,
                      const int* __restrict__ block_tables,
                      const int* __restrict__ context_lens,
                      float* __restrict__ ws,
                      int* __restrict__ ctr,
                      float* __restrict__ out) {
    const int h   = blockIdx.x;
    const int b   = blockIdx.y;
    const int c   = blockIdx.z;
    const int tid = threadIdx.x;  // 0..63

    const int ctx = context_lens[b];
    const int nb  = (ctx + BLOCK_SZ - 1) / BLOCK_SZ;
    const int nch = (nb + CHUNK_BLOCKS - 1) / CHUNK_BLOCKS;
    const int d0 = tid, d1 = tid + 64;

    if (c < NCHUNK) {
        // ================= chunk path (R2-exact) =================
        const int b0 = c * CHUNK_BLOCKS;
        if (b0 >= nb) return;                    // inactive chunk
        const int nbl  = min(nb - b0, CHUNK_BLOCKS);
        const int last = ctx - 1;                // stale cache slot -> masked

        __shared__ float q_lds[Q_PER_KV * HEAD_SIZE];   // 2 KB, pre-scaled
        __shared__ float s_lds[Q_PER_KV * CHUNK_TOK];   // 4 KB scores -> probs

        // stage Q (512 floats = 128 v4f), folding SCALE
        {
            const v4f* qg = reinterpret_cast<const v4f*>(
                query + ((size_t)b * NUM_HEADS + h * Q_PER_KV) * HEAD_SIZE);
            v4f* ql = reinterpret_cast<v4f*>(q_lds);
            ql[tid]      = qg[tid]      * SCALE;
            ql[tid + 64] = qg[tid + 64] * SCALE;
        }
        __syncthreads();

        // scores: 4 lanes per cache block
        {
            const int bil = tid >> 2;   // 0..15
            const int o   = tid & 3;
            if (bil < nbl) {
                const int phys = block_tables[b * MAX_BLOCKS + b0 + bil];
                const v4f* kp = reinterpret_cast<const v4f*>(key_cache) +
                                ((size_t)phys * NUM_KV_HEADS + h) * (HEAD_SIZE * BLOCK_SZ / 4);
                const v4f* q4 = reinterpret_cast<const v4f*>(q_lds);
                v4f acc[Q_PER_KV];
                #pragma unroll
                for (int qh = 0; qh < Q_PER_KV; ++qh) acc[qh] = (v4f)0.f;
                #pragma unroll 4
                for (int d4 = 0; d4 < HEAD_SIZE / 4; ++d4) {
                    v4f k[4];
                    #pragma unroll
                    for (int dd = 0; dd < 4; ++dd) k[dd] = kp[d4 * 16 + dd * 4 + o];
                    #pragma unroll
                    for (int qh = 0; qh < Q_PER_KV; ++qh) {
                        const v4f qv = q4[qh * (HEAD_SIZE / 4) + d4];
                        #pragma unroll
                        for (int dd = 0; dd < 4; ++dd) acc[qh] += qv[dd] * k[dd];
                    }
                }
                const int t0 = bil * BLOCK_SZ + o * 4;
                const int g0 = b0 * BLOCK_SZ + t0;
                #pragma unroll
                for (int qh = 0; qh < Q_PER_KV; ++qh) {
                    v4f sv;
                    #pragma unroll
                    for (int j = 0; j < 4; ++j) {
                        const int g = g0 + j;
                        sv[j] = (g < ctx && g != last) ? acc[qh][j] : -FLT_MAX;
                    }
                    *reinterpret_cast<v4f*>(&s_lds[qh * CHUNK_TOK + t0]) = sv;
                }
            }
        }
        __syncthreads();

        // chunk-local softmax (un-normalized), qh sequential
        float* wsp = ws + (((size_t)b * NUM_KV_HEADS + h) * NCHUNK + c) * WS_STRIDE;
        {
            const int T = nbl * BLOCK_SZ;   // <= 256
            #pragma unroll
            for (int qh = 0; qh < Q_PER_KV; ++qh) {
                float m = -FLT_MAX;
                for (int t = tid; t < T; t += 64) m = fmaxf(m, s_lds[qh * CHUNK_TOK + t]);
                #pragma unroll
                for (int off = 32; off; off >>= 1) m = fmaxf(m, __shfl_xor(m, off));
                float l = 0.f;
                for (int t = tid; t < T; t += 64) {
                    const float s = s_lds[qh * CHUNK_TOK + t];
                    const float p = (s == -FLT_MAX) ? 0.f : __expf(s - m);
                    s_lds[qh * CHUNK_TOK + t] = p;
                    l += p;
                }
                #pragma unroll
                for (int off = 32; off; off >>= 1) l += __shfl_xor(l, off);
                if (tid == 0) { wsp[qh] = m; wsp[Q_PER_KV + qh] = l; }
            }
        }
        __syncthreads();

        // partial PV: lane owns dims {d0,d1} (R2-exact, no double-buffer)
        {
            float acc0[Q_PER_KV] = {0.f, 0.f, 0.f, 0.f};
            float acc1[Q_PER_KV] = {0.f, 0.f, 0.f, 0.f};
            for (int bil = 0; bil < nbl; ++bil) {
                const int phys = block_tables[b * MAX_BLOCKS + b0 + bil];
                const v4f* vp = reinterpret_cast<const v4f*>(value_cache) +
                                ((size_t)phys * NUM_KV_HEADS + h) * (HEAD_SIZE * BLOCK_SZ / 4);
                v4f vv0[4], vv1[4];
                #pragma unroll
                for (int j = 0; j < 4; ++j) { vv0[j] = vp[d0 * 4 + j]; vv1[j] = vp[d1 * 4 + j]; }
                #pragma unroll
                for (int qh = 0; qh < Q_PER_KV; ++qh) {
                    const v4f* pq = reinterpret_cast<const v4f*>(
                        &s_lds[qh * CHUNK_TOK + bil * BLOCK_SZ]);
                    #pragma unroll
                    for (int j = 0; j < 4; ++j) {
                        const v4f p = pq[j];
                        acc0[qh] += p[0]*vv0[j][0] + p[1]*vv0[j][1] + p[2]*vv0[j][2] + p[3]*vv0[j][3];
                        acc1[qh] += p[0]*vv1[j][0] + p[1]*vv1[j][1] + p[2]*vv1[j][2] + p[3]*vv1[j][3];
                    }
                }
            }
            float* wo = wsp + 2 * Q_PER_KV;
            #pragma unroll
            for (int qh = 0; qh < Q_PER_KV; ++qh) {
                wo[qh * HEAD_SIZE + d0] = acc0[qh];
                wo[qh * HEAD_SIZE + d1] = acc1[qh];
            }
        }

        // release: make record visible, then count in
        __syncthreads();
        __threadfence();
        if (tid == 0) atomicAdd(&ctr[b * NUM_KV_HEADS + h], 1);
        return;
    }

    // ================= merge path (c == NCHUNK) =================
    {
        // spin until all nch chunk records for this (b,h) are published
        if (tid == 0) {
            while (__hip_atomic_load(&ctr[b * NUM_KV_HEADS + h],
                                     __ATOMIC_ACQUIRE, __HIP_MEMORY_SCOPE_AGENT) < nch)
                __builtin_amdgcn_s_sleep(8);
        }
        __syncthreads();
        __threadfence();   // acquire side: invalidate before reading records

        const float* wsb = ws + ((size_t)b * NUM_KV_HEADS + h) * NCHUNK * WS_STRIDE;
        float M[Q_PER_KV], L[Q_PER_KV], a0[Q_PER_KV], a1[Q_PER_KV];
        #pragma unroll
        for (int qh = 0; qh < Q_PER_KV; ++qh) { M[qh] = -FLT_MAX; L[qh] = 0.f; a0[qh] = 0.f; a1[qh] = 0.f; }

        for (int cc = 0; cc < nch; ++cc) {
            const float* rp = wsb + (size_t)cc * WS_STRIDE;
            #pragma unroll
            for (int qh = 0; qh < Q_PER_KV; ++qh) {
                const float mc = rp[qh];
                const float lc = rp[Q_PER_KV + qh];
                const float o0 = rp[2 * Q_PER_KV + qh * HEAD_SIZE + d0];
                const float o1 = rp[2 * Q_PER_KV + qh * HEAD_SIZE + d1];
                const float nM = fmaxf(M[qh], mc);
                const float eM = __expf(M[qh] - nM), ec = __expf(mc - nM);
                a0[qh] = a0[qh] * eM + o0 * ec;
                a1[qh] = a1[qh] * eM + o1 * ec;
                L[qh]  = L[qh]  * eM + lc * ec;
                M[qh]  = nM;
            }
        }
        // new token: exact from k_new/v_new
        const float* kn = k_new + ((size_t)b * NUM_KV_HEADS + h) * HEAD_SIZE;
        const float* vn = v_new + ((size_t)b * NUM_KV_HEADS + h) * HEAD_SIZE;
        const float* qb = query + ((size_t)b * NUM_HEADS + h * Q_PER_KV) * HEAD_SIZE;
        const float kn0 = kn[d0], kn1 = kn[d1];
        const float vn0 = vn[d0], vn1 = vn[d1];
        #pragma unroll
        for (int qh = 0; qh < Q_PER_KV; ++qh) {
            float s = (qb[qh * HEAD_SIZE + d0] * kn0 + qb[qh * HEAD_SIZE + d1] * kn1) * SCALE;
            #pragma unroll
            for (int off = 32; off; off >>= 1) s += __shfl_xor(s, off);
            const float nM = fmaxf(M[qh], s);
            const float eM = __expf(M[qh] - nM), es = __expf(s - nM);
            a0[qh] = a0[qh] * eM + es * vn0;
            a1[qh] = a1[qh] * eM + es * vn1;
            L[qh]  = L[qh]  * eM + es;
        }
        float* ob = out + ((size_t)b * NUM_HEADS + h * Q_PER_KV) * HEAD_SIZE;
        #pragma unroll
        for (int qh = 0; qh < Q_PER_KV; ++qh) {
            const float inv = 1.0f / L[qh];
            ob[qh * HEAD_SIZE + d0] = a0[qh] * inv;
            ob[qh * HEAD_SIZE + d1] = a1[qh] * inv;
        }
    }
}

extern "C" void kernel_launch(void* const* d_in, const int* in_sizes, int n_in,
                              void* d_out, int out_size, void* d_ws, size_t ws_size,
                              hipStream_t stream) {
    const float* query       = (const float*)d_in[0];
    const float* k_new       = (const float*)d_in[1];
    const float* v_new       = (const float*)d_in[2];
    const float* key_cache   = (const float*)d_in[3];
    const float* value_cache = (const float*)d_in[4];
    const int*   block_tables  = (const int*)d_in[5];
    const int*   context_lens  = (const int*)d_in[6];
    float* out = (float*)d_out;
    float* ws  = (float*)d_ws;
    int*   ctr = (int*)(ws + CTR_FLT_OFF);

    const int batch = in_sizes[6];

    hipMemsetAsync(ctr, 0, batch * NUM_KV_HEADS * sizeof(int), stream);

    dim3 g(NUM_KV_HEADS, batch, NCHUNK + 1);   // c slowest; merge WGs dispatch last
    paged_attn_fused<<<g, 64, 0, stream>>>(query, k_new, v_new,
                                           key_cache, value_cache,
                                           block_tables, context_lens,
                                           ws, ctr, out);
}

// Round 8
// 79.518 us; speedup vs baseline: 2.9871x; 2.9535x over previous
//
#include <hip/hip_runtime.h>
#include <float.h>

#define NUM_HEADS    32
#define NUM_KV_HEADS 8
#define HEAD_SIZE    128
#define Q_PER_KV     4
#define BLOCK_SZ     16
#define MAX_BLOCKS   128
#define SCALE        0.08838834764831845f

#define CHUNK_BLOCKS 16                           // R2-proven per-WG efficiency
#define CHUNK_TOK    (CHUNK_BLOCKS * BLOCK_SZ)    // 256 tokens
#define NCHUNK       (MAX_BLOCKS / CHUNK_BLOCKS)  // 8
#define WS_STRIDE    528                          // 8 (m,l) + 512 (O)

typedef float v4f __attribute__((ext_vector_type(4)));

// ---------------- kernel 1: per-chunk partial attention ----------------
// grid (NCHUNK, NUM_KV_HEADS, BATCH) -- chunk index FASTEST: the 8 chunks of
// one (b,h) land on 8 different CUs (per-CU byte balance), unlike R2's order.
// 64 threads = 1 wave. bounds(64,4): 128-VGPR budget; R7 measured 64, no spill.
__global__ __launch_bounds__(64, 4)
void paged_attn_chunk(const float* __restrict__ query,
                      const float* __restrict__ key_cache,
                      const float* __restrict__ value_cache,
                      const int* __restrict__ block_tables,
                      const int* __restrict__ context_lens,
                      float* __restrict__ ws) {
    const int c   = blockIdx.x;
    const int h   = blockIdx.y;
    const int b   = blockIdx.z;
    const int tid = threadIdx.x;  // 0..63

    const int ctx = context_lens[b];
    const int nb  = (ctx + BLOCK_SZ - 1) / BLOCK_SZ;
    const int b0  = c * CHUNK_BLOCKS;
    if (b0 >= nb) return;                     // inactive chunk; reducer skips
    const int nbl  = min(nb - b0, CHUNK_BLOCKS);
    const int last = ctx - 1;                 // stale cache slot -> masked here

    __shared__ float q_lds[Q_PER_KV * HEAD_SIZE];   // 2 KB, pre-scaled
    __shared__ float s_lds[Q_PER_KV * CHUNK_TOK];   // 4 KB scores -> probs

    // ---- stage Q (512 floats = 128 v4f), folding SCALE ----
    {
        const v4f* qg = reinterpret_cast<const v4f*>(
            query + ((size_t)b * NUM_HEADS + h * Q_PER_KV) * HEAD_SIZE);
        v4f* ql = reinterpret_cast<v4f*>(q_lds);
        ql[tid]      = qg[tid]      * SCALE;
        ql[tid + 64] = qg[tid + 64] * SCALE;
    }
    __syncthreads();

    // ---- scores: 4 lanes per cache block (R2-exact) ----
    {
        const int bil = tid >> 2;   // 0..15
        const int o   = tid & 3;
        if (bil < nbl) {
            const int phys = block_tables[b * MAX_BLOCKS + b0 + bil];
            const v4f* kp = reinterpret_cast<const v4f*>(key_cache) +
                            ((size_t)phys * NUM_KV_HEADS + h) * (HEAD_SIZE * BLOCK_SZ / 4);
            const v4f* q4 = reinterpret_cast<const v4f*>(q_lds);
            v4f acc[Q_PER_KV];
            #pragma unroll
            for (int qh = 0; qh < Q_PER_KV; ++qh) acc[qh] = (v4f)0.f;
            #pragma unroll 4
            for (int d4 = 0; d4 < HEAD_SIZE / 4; ++d4) {
                v4f k[4];
                #pragma unroll
                for (int dd = 0; dd < 4; ++dd) k[dd] = kp[d4 * 16 + dd * 4 + o];
                #pragma unroll
                for (int qh = 0; qh < Q_PER_KV; ++qh) {
                    const v4f qv = q4[qh * (HEAD_SIZE / 4) + d4];
                    #pragma unroll
                    for (int dd = 0; dd < 4; ++dd) acc[qh] += qv[dd] * k[dd];
                }
            }
            const int t0 = bil * BLOCK_SZ + o * 4;      // chunk-local token
            const int g0 = b0 * BLOCK_SZ + t0;          // global token
            #pragma unroll
            for (int qh = 0; qh < Q_PER_KV; ++qh) {
                v4f sv;
                #pragma unroll
                for (int j = 0; j < 4; ++j) {
                    const int g = g0 + j;
                    sv[j] = (g < ctx && g != last) ? acc[qh][j] : -FLT_MAX;
                }
                *reinterpret_cast<v4f*>(&s_lds[qh * CHUNK_TOK + t0]) = sv;
            }
        }
    }
    __syncthreads();

    // ---- chunk-local softmax (un-normalized), qh sequential (R2-exact) ----
    float* wsp = ws + (((size_t)b * NUM_KV_HEADS + h) * NCHUNK + c) * WS_STRIDE;
    {
        const int T = nbl * BLOCK_SZ;   // <= 256
        #pragma unroll
        for (int qh = 0; qh < Q_PER_KV; ++qh) {
            float m = -FLT_MAX;
            for (int t = tid; t < T; t += 64) m = fmaxf(m, s_lds[qh * CHUNK_TOK + t]);
            #pragma unroll
            for (int off = 32; off; off >>= 1) m = fmaxf(m, __shfl_xor(m, off));
            float l = 0.f;
            for (int t = tid; t < T; t += 64) {
                const float s = s_lds[qh * CHUNK_TOK + t];
                const float p = (s == -FLT_MAX) ? 0.f : __expf(s - m);
                s_lds[qh * CHUNK_TOK + t] = p;
                l += p;
            }
            #pragma unroll
            for (int off = 32; off; off >>= 1) l += __shfl_xor(l, off);
            if (tid == 0) { wsp[qh] = m; wsp[Q_PER_KV + qh] = l; }
        }
    }
    __syncthreads();

    // ---- partial PV: lane owns dims {tid, tid+64} (R2-exact) ----
    {
        const int d0 = tid, d1 = tid + 64;
        float acc0[Q_PER_KV] = {0.f, 0.f, 0.f, 0.f};
        float acc1[Q_PER_KV] = {0.f, 0.f, 0.f, 0.f};
        for (int bil = 0; bil < nbl; ++bil) {
            const int phys = block_tables[b * MAX_BLOCKS + b0 + bil];
            const v4f* vp = reinterpret_cast<const v4f*>(value_cache) +
                            ((size_t)phys * NUM_KV_HEADS + h) * (HEAD_SIZE * BLOCK_SZ / 4);
            v4f vv0[4], vv1[4];
            #pragma unroll
            for (int j = 0; j < 4; ++j) { vv0[j] = vp[d0 * 4 + j]; vv1[j] = vp[d1 * 4 + j]; }
            #pragma unroll
            for (int qh = 0; qh < Q_PER_KV; ++qh) {
                const v4f* pq = reinterpret_cast<const v4f*>(
                    &s_lds[qh * CHUNK_TOK + bil * BLOCK_SZ]);
                #pragma unroll
                for (int j = 0; j < 4; ++j) {
                    const v4f p = pq[j];
                    acc0[qh] += p[0]*vv0[j][0] + p[1]*vv0[j][1] + p[2]*vv0[j][2] + p[3]*vv0[j][3];
                    acc1[qh] += p[0]*vv1[j][0] + p[1]*vv1[j][1] + p[2]*vv1[j][2] + p[3]*vv1[j][3];
                }
            }
        }
        float* wo = wsp + 2 * Q_PER_KV;
        #pragma unroll
        for (int qh = 0; qh < Q_PER_KV; ++qh) {
            wo[qh * HEAD_SIZE + d0] = acc0[qh];
            wo[qh * HEAD_SIZE + d1] = acc1[qh];
        }
    }
}

// ---------------- kernel 2: merge chunks + new token + normalize ----------------
// grid (NUM_KV_HEADS, BATCH), 512 threads (R2-exact).
__global__ __launch_bounds__(512, 2)
void paged_attn_reduce(const float* __restrict__ query,
                       const float* __restrict__ k_new,
                       const float* __restrict__ v_new,
                       const int* __restrict__ context_lens,
                       const float* __restrict__ ws,
                       float* __restrict__ out) {
    const int h   = blockIdx.x;
    const int b   = blockIdx.y;
    const int tid = threadIdx.x;

    __shared__ float snew_lds[Q_PER_KV];

    const int ctx = context_lens[b];
    const int nb  = (ctx + BLOCK_SZ - 1) / BLOCK_SZ;
    const int nch = (nb + CHUNK_BLOCKS - 1) / CHUNK_BLOCKS;

    // s_new[qh] = SCALE * q[qh] . k_new   (4 waves, one per qh)
    if (tid < 4 * 64) {
        const int w = tid >> 6, lane = tid & 63;
        const float* qp = query + ((size_t)b * NUM_HEADS + h * Q_PER_KV + w) * HEAD_SIZE;
        const float* kn = k_new + ((size_t)b * NUM_KV_HEADS + h) * HEAD_SIZE;
        float v = qp[lane] * kn[lane] + qp[lane + 64] * kn[lane + 64];
        #pragma unroll
        for (int off = 32; off; off >>= 1) v += __shfl_xor(v, off);
        if (lane == 0) snew_lds[w] = v * SCALE;
    }
    __syncthreads();

    const int qh = tid >> 7, d = tid & 127;
    const float* wsb = ws + ((size_t)b * NUM_KV_HEADS + h) * NCHUNK * WS_STRIDE;

    float M = -FLT_MAX, L = 0.f, acc = 0.f;
    for (int c = 0; c < nch; ++c) {
        const float* wsp = wsb + (size_t)c * WS_STRIDE;
        const float mc = wsp[qh];
        const float lc = wsp[Q_PER_KV + qh];
        const float oc = wsp[2 * Q_PER_KV + qh * HEAD_SIZE + d];
        const float nM = fmaxf(M, mc);
        const float eM = __expf(M - nM), ec = __expf(mc - nM);
        acc = acc * eM + oc * ec;
        L   = L   * eM + lc * ec;
        M   = nM;
    }
    // new token (exact, from k_new/v_new)
    {
        const float s  = snew_lds[qh];
        const float nM = fmaxf(M, s);
        const float eM = __expf(M - nM), es = __expf(s - nM);
        const float vn = v_new[((size_t)b * NUM_KV_HEADS + h) * HEAD_SIZE + d];
        acc = acc * eM + es * vn;
        L   = L   * eM + es;
    }
    out[((size_t)b * NUM_HEADS + h * Q_PER_KV + qh) * HEAD_SIZE + d] = acc / L;
}

extern "C" void kernel_launch(void* const* d_in, const int* in_sizes, int n_in,
                              void* d_out, int out_size, void* d_ws, size_t ws_size,
                              hipStream_t stream) {
    const float* query       = (const float*)d_in[0];
    const float* k_new       = (const float*)d_in[1];
    const float* v_new       = (const float*)d_in[2];
    const float* key_cache   = (const float*)d_in[3];
    const float* value_cache = (const float*)d_in[4];
    const int*   block_tables  = (const int*)d_in[5];
    const int*   context_lens  = (const int*)d_in[6];
    float* out = (float*)d_out;
    float* ws  = (float*)d_ws;

    const int batch = in_sizes[6];

    dim3 g1(NCHUNK, NUM_KV_HEADS, batch);   // chunk index fastest (balance)
    paged_attn_chunk<<<g1, 64, 0, stream>>>(query, key_cache, value_cache,
                                            block_tables, context_lens, ws);
    dim3 g2(NUM_KV_HEADS, batch);
    paged_attn_reduce<<<g2, 512, 0, stream>>>(query, k_new, v_new,
                                              context_lens, ws, out);
}